// Round 13
// baseline (282.285 us; speedup 1.0000x reference)
//
#include <hip/hip_runtime.h>

#define PRIOR_SCALE 0.3f
#define NEGF (-1e30f)
#define LOG2E_F 1.4426950408889634f
#define LN2_F 0.6931471805599453f
#define K_SS 8     // time steps per superstep (one barrier per K_SS steps)
#define MARG 24    // max adjacent-lane exponent gap after relaxation
#define PB 512     // prepass blocks / prior stripes

// Fused waitcnt+barrier: ONE asm block with "memory" clobber (round-5 lesson).
#define PHASE_BARRIER() \
  asm volatile("s_waitcnt lgkmcnt(0)\n\ts_barrier" ::: "memory")

__device__ __forceinline__ float fexp2(float x) { return __builtin_amdgcn_exp2f(x); }
__device__ __forceinline__ float flog2(float x) { return __builtin_amdgcn_logf(x); }

__device__ __forceinline__ float lse2b(float a, float b) {
  float m = fmaxf(a, b);
  float d = fminf(a, b) - m;
  return m + flog2(1.0f + fexp2(d));
}

// lane-1 -> lane shift via DPP wave_shr:1. Lane 0 receives `fill`.
__device__ __forceinline__ float shr1_dpp(float x, float fill) {
  return __int_as_float(__builtin_amdgcn_update_dpp(
      __float_as_int(fill), __float_as_int(x), 0x138 /*wave_shr:1*/, 0xF, 0xF, false));
}
__device__ __forceinline__ int shr1_dpp_i(int x, int fill) {
  return __builtin_amdgcn_update_dpp(fill, x, 0x138, 0xF, 0xF, false);
}
template <int CTRL, int RM>
__device__ __forceinline__ int dppi(int x) {   // raw dpp shift (unshifted lanes keep x)
  return __builtin_amdgcn_update_dpp(x, x, CTRL, RM, 0xF, false);
}
__device__ __forceinline__ int imax2(int a, int b) { return a > b ? a : b; }

// Un-sinkable prefetch: asm-pinned global_load_dword pair.
__device__ __forceinline__ void issue_pair(float& e, float& b, uint32_t offE,
                                           uint32_t offB, uint64_t base) {
  asm volatile("global_load_dword %0, %2, %4\n\t"
               "global_load_dword %1, %3, %4"
               : "=v"(e), "=v"(b)
               : "v"(offE), "v"(offB), "s"(base));
}
// Counted wait tied to consumed values via data dependency (rule #18).
__device__ __forceinline__ void wait_pair(float& e, float& b) {
  asm volatile("s_waitcnt vmcnt(14)" : "+v"(e), "+v"(b));
}

// =====================================================================
// Pre-pass: stream lp coalesced once; fuse (a) prior exp-sum partials and
// (b) the emission gather, writing LINEAR pre-scaled emissions:
// Eodd[n][t][s] = 2^(fma(lp[t][n][tgt[n][s]], LOG2E, pe[n][s])); Ebl likewise.
// =====================================================================
extern "C" __global__ void __launch_bounds__(256)
prep_kernel(const float* __restrict__ lp, const float* __restrict__ lpri,
            const int* __restrict__ tgt, const int* __restrict__ ilen,
            float* __restrict__ Eodd, float* __restrict__ Ebl,
            float* __restrict__ partial, int T, int N, int V, int S) {
  const int tid = threadIdx.x;
  const int b = blockIdx.x;          // t-stripe: t = b, b+PB, ...
  __shared__ int   stv[32 * 256];
  __shared__ float spe[32 * 256];
  __shared__ int   slen[32];
  for (int idx = tid; idx < N * 256; idx += 256) {
    int vv = tgt[idx];
    stv[idx] = vv;
    spe[idx] = (-PRIOR_SCALE * lpri[vv]) * LOG2E_F;
  }
  if (tid < N) slen[tid] = ilen[tid];
  const float epb = (-PRIOR_SCALE * lpri[0]) * LOG2E_F;
  __syncthreads();

  float psum = 0.0f;
  for (int t = b; t < T; t += PB) {
#pragma unroll 2
    for (int n = 0; n < 32; ++n) {
      const float* row = lp + ((size_t)t * N + n) * V;
      float val = row[tid];                       // coalesced 1KB row read
      if (t < slen[n]) psum += __expf(val);       // prior accumulation
      float ev = row[stv[n * 256 + tid]];         // scattered but L1-hot
      Eodd[((size_t)n * T + t) * 256 + tid] =
          fexp2(fmaf(ev, LOG2E_F, spe[n * 256 + tid]));
      if (tid == 0) Ebl[(size_t)n * T + t] = fexp2(fmaf(row[0], LOG2E_F, epb));
    }
  }
  partial[(size_t)b * 256 + tid] = psum;
}

// =====================================================================
// Serial scan: r12 block-float structure (4 skewed waves, 2 positions/lane,
// per-lane exponents with decay-prefix-max relaxation), but per-step loads
// are 1 coalesced dword (Eodd) + 1 uniform dword (Ebl); no trans ops at all
// in the steady-state step.
// =====================================================================
extern "C" __global__ void __launch_bounds__(256, 1)
ctc_scan_kernel(const float* __restrict__ ws_f, const int* __restrict__ tgt,
                const int* __restrict__ ilen, const int* __restrict__ tlen,
                float* __restrict__ nll, int T, int N, int S) {
  const int n = blockIdx.x;
  const int g = threadIdx.x;   // owns positions 2g (blank), 2g+1 (label g)
  const int lane = g & 63;
  const int wid = __builtin_amdgcn_readfirstlane(threadIdx.x >> 6);
  __shared__ __align__(16) float mb[3][2048];  // raw x1 mantissas (writer scale)
  __shared__ int mbe[3][256];                  // writer's per-superstep exponent
  __shared__ float afin[513];

  const int len = __builtin_amdgcn_readfirstlane(ilen[n]);
  const int tl = tlen[n];

  const int* trow = tgt + n * S;
  const int tv = trow[g];
  const int tvp = (g > 0) ? trow[g - 1] : -1;
  const float skf = (g > 0 && tv != tvp) ? 1.0f : 0.0f;
  const int penB = MARG * ((lane & 15) + 1);   // bcast15 per-lane distance penalty
  const int penC = MARG * ((lane & 31) + 1);   // bcast31 per-lane distance penalty

  // Eodd region for n: ws + n*T*256 ; Ebl[n][t]: ws + N*T*256 + n*T
  const float* eoddn = ws_f + (size_t)n * T * 256;
  const uint64_t gbase = (uint64_t)(uintptr_t)eoddn;
  const uint32_t eblOffB = (uint32_t)((((size_t)(N - n) * T) * 256 + (size_t)n * T) * 4);
  const uint32_t gb4 = (uint32_t)g * 4u;

  // alpha init (t=0): linear mantissas (pre-exponentiated by prep), e=0
  float x0 = 0.0f, x1 = 0.0f, x2 = 0.0f;
  int e = 0;
  if (g == 0) {
    x0 = ws_f[(size_t)N * T * 256 + (size_t)n * T];  // Ebl[n][0]
    x1 = eoddn[0];                                   // Eodd[n][0][0]
  }
  // mailbox init: 0 mantissa = no mass
  for (int idx = g; idx < 3 * 2048; idx += 256) ((float*)mb)[idx] = 0.0f;
  for (int idx = g; idx < 3 * 256; idx += 256) ((int*)mbe)[idx] = 0;

  // ---- emission ring: 8 named (odd, blank) linear pairs, asm-pinned ----
  float eR0, eR1, eR2, eR3, eR4, eR5, eR6, eR7;
  float bR0, bR1, bR2, bR3, bR4, bR5, bR6, bR7;
#define PRO(K) { uint32_t tt = (uint32_t)((1 + K < len) ? (1 + K) : (len - 1)); \
                 issue_pair(eR##K, bR##K, tt * 1024u + gb4, eblOffB + tt * 4u, gbase); }
  PRO(0) PRO(1) PRO(2) PRO(3) PRO(4) PRO(5) PRO(6) PRO(7)
#undef PRO
  uint32_t ofE, ofBl;
  { uint32_t tn = (uint32_t)((1 + K_SS < len) ? (1 + K_SS) : (len - 1));
    ofE = tn * 1024u; ofBl = eblOffB + tn * 4u; }

  float mv0 = 0, mv1 = 0, mv2 = 0, mv3 = 0, mv4 = 0, mv5 = 0, mv6 = 0, mv7 = 0;

  PHASE_BARRIER();  // mailbox init visible

  const int nss = (len - 1 + K_SS - 1) / K_SS;
  const int P = nss + 3;

#define STEP(KK, T_, DSC_) {                                                   \
    const int t = (T_);                                                        \
    if (t < len) {                                                             \
      wait_pair(eR##KK, bR##KK);                                               \
      float e1  = eR##KK;                                                      \
      float ebl = bR##KK;                                                      \
      issue_pair(eR##KK, bR##KK, ofE + gb4, ofBl, gbase);                      \
      bool adv = ((t + 1 + K_SS) < len);                                       \
      ofE  += adv ? 1024u : 0u;                                                \
      ofBl += adv ? 4u : 0u;                                                   \
      float am1 = ldexpf(shr1_dpp(x1, mv##KK), (DSC_));                        \
      am1 = fminf(am1, 1.0e33f);   /* insurance vs inf */                      \
      float sel = (g == 255) ? x1 : 0.0f;                                      \
      float y0 = (x0 + am1) * ebl;                                             \
      float y1 = fmaf(skf, am1, x1 + x0) * e1;                                 \
      x2 = (x2 + sel) * ebl;                                                   \
      x0 = y0; x1 = y1;                                                        \
      if (lane == 63 && wid < 3) mb[wid][t] = y1;   /* raw, writer scale */    \
    } }

  for (int p = 0; p < P; ++p) {
    const int i = p - wid;
    if (i >= 0 && i < nss) {
      const int t0 = 1 + i * K_SS;
      int eA = 0, eB = 0;
      if (wid > 0) {
        eB = mbe[wid - 1][i];
        eA = (i > 0) ? mbe[wid - 1][i - 1] : eB;
        const float4* mrow = (const float4*)&mb[wid - 1][t0 - 1];  // 16-aligned
        float4 q0 = mrow[0], q1 = mrow[1];
        mv0 = q0.x; mv1 = q0.y; mv2 = q0.z; mv3 = q0.w;
        mv4 = q1.x; mv5 = q1.y; mv6 = q1.z; mv7 = q1.w;
      }
      // ---- renorm: per-lane peg (max -> 2^40) + decay-prefix-max relaxation ----
      int dscL, dsc0;
      {
        float mxv = fmaxf(fmaxf(x0, x1), x2);
        int ex = (int)((__float_as_uint(mxv) >> 23) & 0xFFu) - 127;
        int ecand = (mxv > 0.0f) ? (e + ex - 40) : -2000000;
        if (wid > 0 && lane == 0) ecand = imax2(ecand, imax2(eA, eB) - MARG);
        int v = ecand;
        v = imax2(v, dppi<0x111, 0xF>(v) - MARG);       // row_shr:1
        v = imax2(v, dppi<0x112, 0xF>(v) - 2 * MARG);   // row_shr:2
        v = imax2(v, dppi<0x114, 0xF>(v) - 4 * MARG);   // row_shr:4
        v = imax2(v, dppi<0x118, 0xF>(v) - 8 * MARG);   // row_shr:8
        v = imax2(v, dppi<0x142, 0xA>(v) - penB);       // row_bcast:15 -> rows 1,3
        v = imax2(v, dppi<0x143, 0xC>(v) - penC);       // row_bcast:31 -> rows 2,3
        int dsc = e - v;
        x0 = ldexpf(x0, dsc);
        x1 = ldexpf(x1, dsc);
        x2 = ldexpf(x2, dsc);
        e = v;
        if (lane == 63 && wid < 3) mbe[wid][i] = e;
        int eprevL = shr1_dpp_i(e, eB);
        dscL = eprevL - e;                 // <= MARG by relaxation
        dsc0 = (lane == 0) ? (eA - e) : dscL;  // step-0 fill is in eA scale
      }
      STEP(0, t0 + 0, dsc0)  STEP(1, t0 + 1, dscL)
      STEP(2, t0 + 2, dscL)  STEP(3, t0 + 3, dscL)
      STEP(4, t0 + 4, dscL)  STEP(5, t0 + 5, dscL)
      STEP(6, t0 + 6, dscL)  STEP(7, t0 + 7, dscL)
    }
    PHASE_BARRIER();
  }
#undef STEP

  // drain outstanding asm loads, keep dest regs live until drained
  asm volatile("s_waitcnt vmcnt(0)");
  asm volatile("" :: "v"(eR0), "v"(eR1), "v"(eR2), "v"(eR3),
                     "v"(eR4), "v"(eR5), "v"(eR6), "v"(eR7));
  asm volatile("" :: "v"(bR0), "v"(bR1), "v"(bR2), "v"(bR3),
                     "v"(bR4), "v"(bR5), "v"(bR6), "v"(bR7));

  // final alphas in absolute log2: log2(x) + e
  const float ef = (float)e;
  afin[2 * g]     = fmaxf(flog2(x0) + ef, NEGF);
  afin[2 * g + 1] = fmaxf(flog2(x1) + ef, NEGF);
  if (g == 255) afin[512] = fmaxf(flog2(x2) + ef, NEGF);
  __syncthreads();
  if (g == 0) {
    const int i1 = 2 * tl;
    float ll = lse2b(afin[i1], afin[i1 - 1]) * LN2_F;
    nll[n] = -ll / (float)tl;
  }
}

// two-stage finalize
extern "C" __global__ void __launch_bounds__(256)
finalize1_kernel(const float* __restrict__ partial, float* __restrict__ partial2) {
  const int v = threadIdx.x;
  const int b = blockIdx.x;   // 32 blocks
  float s = 0.0f;
#pragma unroll 4
  for (int pb = b; pb < PB; pb += 32) s += partial[(size_t)pb * 256 + v];
  partial2[(size_t)b * 256 + v] = s;
}
extern "C" __global__ void __launch_bounds__(256)
finalize2_kernel(const float* __restrict__ partial2, const float* __restrict__ nll,
                 float* __restrict__ out, int N) {
  const int v = threadIdx.x;
  float s = 0.0f;
#pragma unroll
  for (int b = 0; b < 32; ++b) s += partial2[(size_t)b * 256 + v];
  out[1 + v] = __logf(s);
  if (v == 0) {
    float acc = 0.0f;
#pragma unroll 8
    for (int i = 0; i < N; ++i) acc += nll[i];
    out[0] = acc / (float)N;
  }
}

// =====================================================================
// Fallback (ws too small): round-12 fused kernel (verified), verbatim.
// =====================================================================
extern "C" __global__ void __launch_bounds__(256, 1)
ctc_fused_r12(const float* __restrict__ lp, const float* __restrict__ lpri,
              const int* __restrict__ tgt, const int* __restrict__ ilen,
              const int* __restrict__ tlen, float* __restrict__ nll,
              float* __restrict__ partial, int pblocks,
              int T, int N, int V, int S) {
  if ((int)blockIdx.x >= N) {
    const int pb = blockIdx.x - N;
    const int v = threadIdx.x;
    float s = 0.0f;
    for (int t = pb; t < T; t += pblocks) {
      const float* base = lp + (size_t)t * N * V + v;
      for (int nn = 0; nn < N; ++nn) {
        float x = base[(size_t)nn * V];
        s += (t < ilen[nn]) ? __expf(x) : 0.0f;
      }
    }
    partial[(size_t)pb * V + v] = s;
    return;
  }
  const int n = blockIdx.x;
  const int g = threadIdx.x;
  const int lane = g & 63;
  const int wid = __builtin_amdgcn_readfirstlane(threadIdx.x >> 6);
  __shared__ __align__(16) float mb[3][2048];
  __shared__ int mbe[3][256];
  __shared__ float afin[513];
  const int len = __builtin_amdgcn_readfirstlane(ilen[n]);
  const int tl = tlen[n];
  const int* trow = tgt + n * S;
  const int tv = trow[g];
  const int tvp = (g > 0) ? trow[g - 1] : -1;
  const float skf = (g > 0 && tv != tvp) ? 1.0f : 0.0f;
  const float ep1 = (-PRIOR_SCALE * lpri[tv]) * LOG2E_F;
  const float epb = (-PRIOR_SCALE * lpri[0]) * LOG2E_F;
  const int penB = MARG * ((lane & 15) + 1);
  const int penC = MARG * ((lane & 31) + 1);
  const float* rp = lp + (size_t)n * V;
  const uint32_t RBu = (uint32_t)(N * V * 4);
  const uint32_t tvb = (uint32_t)tv * 4u;
  const uint64_t gbase = (uint64_t)(uintptr_t)rp;
  float x0 = 0.0f, x1 = 0.0f, x2 = 0.0f;
  int e = 0;
  { float b0 = rp[0], e0 = rp[tv];
    if (g == 0) {
      x0 = fexp2(fmaf(b0, LOG2E_F, epb));
      x1 = fexp2(fmaf(e0, LOG2E_F, ep1));
    } }
  for (int idx = g; idx < 3 * 2048; idx += 256) ((float*)mb)[idx] = 0.0f;
  for (int idx = g; idx < 3 * 256; idx += 256) ((int*)mbe)[idx] = 0;
  float eR0, eR1, eR2, eR3, eR4, eR5, eR6, eR7;
  float bR0, bR1, bR2, bR3, bR4, bR5, bR6, bR7;
#define PRO(K) { uint32_t tt = (uint32_t)((1 + K < len) ? (1 + K) : (len - 1)); \
                 issue_pair(eR##K, bR##K, tt * RBu + tvb, tt * RBu, gbase); }
  PRO(0) PRO(1) PRO(2) PRO(3) PRO(4) PRO(5) PRO(6) PRO(7)
#undef PRO
  uint32_t ofB;
  { uint32_t tn = (uint32_t)((1 + K_SS < len) ? (1 + K_SS) : (len - 1));
    ofB = tn * RBu; }
  float mv0 = 0, mv1 = 0, mv2 = 0, mv3 = 0, mv4 = 0, mv5 = 0, mv6 = 0, mv7 = 0;
  PHASE_BARRIER();
  const int nss = (len - 1 + K_SS - 1) / K_SS;
  const int P = nss + 3;
#define STEP(KK, T_, DSC_) {                                                   \
    const int t = (T_);                                                        \
    if (t < len) {                                                             \
      wait_pair(eR##KK, bR##KK);                                               \
      float e1  = fexp2(fmaf(eR##KK, LOG2E_F, ep1));                           \
      float ebl = fexp2(fmaf(bR##KK, LOG2E_F, epb));                           \
      issue_pair(eR##KK, bR##KK, ofB + tvb, ofB, gbase);                       \
      ofB += ((t + 1 + K_SS) < len) ? RBu : 0u;                                \
      float am1 = ldexpf(shr1_dpp(x1, mv##KK), (DSC_));                        \
      am1 = fminf(am1, 1.0e33f);                                               \
      float sel = (g == 255) ? x1 : 0.0f;                                      \
      float y0 = (x0 + am1) * ebl;                                             \
      float y1 = fmaf(skf, am1, x1 + x0) * e1;                                 \
      x2 = (x2 + sel) * ebl;                                                   \
      x0 = y0; x1 = y1;                                                        \
      if (lane == 63 && wid < 3) mb[wid][t] = y1;                              \
    } }
  for (int p = 0; p < P; ++p) {
    const int i = p - wid;
    if (i >= 0 && i < nss) {
      const int t0 = 1 + i * K_SS;
      int eA = 0, eB = 0;
      if (wid > 0) {
        eB = mbe[wid - 1][i];
        eA = (i > 0) ? mbe[wid - 1][i - 1] : eB;
        const float4* mrow = (const float4*)&mb[wid - 1][t0 - 1];
        float4 q0 = mrow[0], q1 = mrow[1];
        mv0 = q0.x; mv1 = q0.y; mv2 = q0.z; mv3 = q0.w;
        mv4 = q1.x; mv5 = q1.y; mv6 = q1.z; mv7 = q1.w;
      }
      int dscL, dsc0;
      {
        float mxv = fmaxf(fmaxf(x0, x1), x2);
        int ex = (int)((__float_as_uint(mxv) >> 23) & 0xFFu) - 127;
        int ecand = (mxv > 0.0f) ? (e + ex - 40) : -2000000;
        if (wid > 0 && lane == 0) ecand = imax2(ecand, imax2(eA, eB) - MARG);
        int v = ecand;
        v = imax2(v, dppi<0x111, 0xF>(v) - MARG);
        v = imax2(v, dppi<0x112, 0xF>(v) - 2 * MARG);
        v = imax2(v, dppi<0x114, 0xF>(v) - 4 * MARG);
        v = imax2(v, dppi<0x118, 0xF>(v) - 8 * MARG);
        v = imax2(v, dppi<0x142, 0xA>(v) - penB);
        v = imax2(v, dppi<0x143, 0xC>(v) - penC);
        int dsc = e - v;
        x0 = ldexpf(x0, dsc);
        x1 = ldexpf(x1, dsc);
        x2 = ldexpf(x2, dsc);
        e = v;
        if (lane == 63 && wid < 3) mbe[wid][i] = e;
        int eprevL = shr1_dpp_i(e, eB);
        dscL = eprevL - e;
        dsc0 = (lane == 0) ? (eA - e) : dscL;
      }
      STEP(0, t0 + 0, dsc0)  STEP(1, t0 + 1, dscL)
      STEP(2, t0 + 2, dscL)  STEP(3, t0 + 3, dscL)
      STEP(4, t0 + 4, dscL)  STEP(5, t0 + 5, dscL)
      STEP(6, t0 + 6, dscL)  STEP(7, t0 + 7, dscL)
    }
    PHASE_BARRIER();
  }
#undef STEP
  asm volatile("s_waitcnt vmcnt(0)");
  asm volatile("" :: "v"(eR0), "v"(eR1), "v"(eR2), "v"(eR3),
                     "v"(eR4), "v"(eR5), "v"(eR6), "v"(eR7));
  asm volatile("" :: "v"(bR0), "v"(bR1), "v"(bR2), "v"(bR3),
                     "v"(bR4), "v"(bR5), "v"(bR6), "v"(bR7));
  const float ef = (float)e;
  afin[2 * g]     = fmaxf(flog2(x0) + ef, NEGF);
  afin[2 * g + 1] = fmaxf(flog2(x1) + ef, NEGF);
  if (g == 255) afin[512] = fmaxf(flog2(x2) + ef, NEGF);
  __syncthreads();
  if (g == 0) {
    const int i1 = 2 * tl;
    float ll = lse2b(afin[i1], afin[i1 - 1]) * LN2_F;
    nll[n] = -ll / (float)tl;
  }
}
extern "C" __global__ void finalize_kernel(const float* __restrict__ partial, int nstripes,
                                           const float* __restrict__ nll,
                                           float* __restrict__ out, int N, int V) {
  const int v = threadIdx.x;
  float s = 0.0f;
#pragma unroll 4
  for (int pb = 0; pb < nstripes; ++pb) s += partial[(size_t)pb * V + v];
  out[1 + v] = __logf(s);
  if (v == 0) {
    float acc = 0.0f;
#pragma unroll 8
    for (int i = 0; i < N; ++i) acc += nll[i];
    out[0] = acc / (float)N;
  }
}

extern "C" void kernel_launch(void* const* d_in, const int* in_sizes, int n_in,
                              void* d_out, int out_size, void* d_ws, size_t ws_size,
                              hipStream_t stream) {
  const float* lp   = (const float*)d_in[0];  // [T,N,V] fp32
  const float* lpri = (const float*)d_in[1];  // [1,V]   fp32
  const int*   tgt  = (const int*)d_in[2];    // [N,S]
  const int*   ilen = (const int*)d_in[3];    // [N]
  const int*   tlen = (const int*)d_in[4];    // [N]
  const int V = in_sizes[1];
  const int N = in_sizes[3];
  const int S = in_sizes[2] / N;
  const int T = in_sizes[0] / (N * V);

  float* out = (float*)d_out;   // [0]=loss, [1..V]=prior logsumexp

  // ws: Eodd [N*T*256] | Ebl [N*T] | partial [PB*256] | partial2 [32*256] | nll [N]
  const size_t eodd_f = (size_t)N * T * 256;
  const size_t ebl_f  = (size_t)N * T;
  const size_t need = (eodd_f + ebl_f + (size_t)PB * 256 + 32 * 256 + N) * sizeof(float);

  if (ws_size >= need) {
    float* ws_f     = (float*)d_ws;
    float* Eodd     = ws_f;
    float* Ebl      = ws_f + eodd_f;
    float* partial  = Ebl + ebl_f;
    float* partial2 = partial + (size_t)PB * 256;
    float* nll      = partial2 + 32 * 256;

    prep_kernel<<<PB, 256, 0, stream>>>(lp, lpri, tgt, ilen, Eodd, Ebl,
                                        partial, T, N, V, S);
    ctc_scan_kernel<<<N, 256, 0, stream>>>(ws_f, tgt, ilen, tlen, nll, T, N, S);
    finalize1_kernel<<<32, 256, 0, stream>>>(partial, partial2);
    finalize2_kernel<<<1, 256, 0, stream>>>(partial2, nll, out, N);
  } else {
    int pblocks = 200;
    size_t need2 = ((size_t)pblocks * V + 64) * sizeof(float);
    if (ws_size < need2) {
      long avail = (long)(ws_size / sizeof(float)) - 64;
      pblocks = (int)(avail / V);
      if (pblocks < 1) pblocks = 1;
    }
    float* partial = (float*)d_ws;
    float* nll = partial + (size_t)pblocks * V;
    ctc_fused_r12<<<N + pblocks, 256, 0, stream>>>(lp, lpri, tgt, ilen, tlen,
                                                   nll, partial, pblocks, T, N, V, S);
    finalize_kernel<<<1, 256, 0, stream>>>(partial, pblocks, nll, out, N, V);
  }
}

// Round 19
// 213.189 us; speedup vs baseline: 1.3241x; 1.3241x over previous
//
#include <hip/hip_runtime.h>

#define PRIOR_SCALE 0.3f
#define NEGF (-1e30f)
#define LOG2E_F 1.4426950408889634f
#define LN2_F 0.6931471805599453f
#define K_SS 8     // time steps per superstep (one barrier per K_SS steps)
#define MARG 24    // max adjacent-lane exponent gap after relaxation

// Fused waitcnt+barrier: ONE asm block with "memory" clobber (round-5 lesson).
#define PHASE_BARRIER() \
  asm volatile("s_waitcnt lgkmcnt(0)\n\ts_barrier" ::: "memory")

__device__ __forceinline__ float fexp2(float x) { return __builtin_amdgcn_exp2f(x); }
__device__ __forceinline__ float flog2(float x) { return __builtin_amdgcn_logf(x); }

__device__ __forceinline__ float lse2b(float a, float b) {
  float m = fmaxf(a, b);
  float d = fminf(a, b) - m;
  return m + flog2(1.0f + fexp2(d));
}

// lane-1 -> lane shift via DPP wave_shr:1. Lane 0 receives `fill`.
__device__ __forceinline__ float shr1_dpp(float x, float fill) {
  return __int_as_float(__builtin_amdgcn_update_dpp(
      __float_as_int(fill), __float_as_int(x), 0x138 /*wave_shr:1*/, 0xF, 0xF, false));
}
__device__ __forceinline__ int shr1_dpp_i(int x, int fill) {
  return __builtin_amdgcn_update_dpp(fill, x, 0x138, 0xF, 0xF, false);
}
template <int CTRL, int RM>
__device__ __forceinline__ int dppi(int x) {   // raw dpp shift (unshifted lanes keep x)
  return __builtin_amdgcn_update_dpp(x, x, CTRL, RM, 0xF, false);
}
__device__ __forceinline__ int imax2(int a, int b) { return a > b ? a : b; }

// Un-sinkable prefetch: asm-pinned global_load_dword pair.
// NOTE: 8-pair ring (16 outstanding) is the proven-safe depth: at the
// resulting ~44 VGPR pressure the allocator never copies/spills a ring
// register between issue and wait. Deeper rings (r14/r17/r18) corrupt.
__device__ __forceinline__ void issue_pair(float& e, float& b, uint32_t offE,
                                           uint32_t offB, uint64_t base) {
  asm volatile("global_load_dword %0, %2, %4\n\t"
               "global_load_dword %1, %3, %4"
               : "=v"(e), "=v"(b)
               : "v"(offE), "v"(offB), "s"(base));
}
// Counted wait tied to consumed values via data dependency (rule #18).
// Ring = 8 pairs = 16 outstanding; wait for the 2 oldest.
__device__ __forceinline__ void wait_pair(float& e, float& b) {
  asm volatile("s_waitcnt vmcnt(14)" : "+v"(e), "+v"(b));
}

// Blocks [0,N): CTC forward, 4 time-skewed waves, 2 positions/lane, LINEAR
// per-lane block-float alphas with relaxation-bounded exponents.
// Blocks [N, N+pblocks): label-prior partial sums on the idle CUs.
extern "C" __global__ void __launch_bounds__(256, 1)
ctc_fused_kernel(const float* __restrict__ lp, const float* __restrict__ lpri,
                 const int* __restrict__ tgt, const int* __restrict__ ilen,
                 const int* __restrict__ tlen, float* __restrict__ nll,
                 float* __restrict__ partial, int pblocks,
                 int T, int N, int V, int S) {
  if ((int)blockIdx.x >= N) {
    const int pb = blockIdx.x - N;
    const int v = threadIdx.x;  // V == 256 == blockDim.x
    float s = 0.0f;
    for (int t = pb; t < T; t += pblocks) {
      const float* base = lp + (size_t)t * N * V + v;
      for (int nn = 0; nn < N; ++nn) {
        float x = base[(size_t)nn * V];
        s += (t < ilen[nn]) ? __expf(x) : 0.0f;
      }
    }
    partial[(size_t)pb * V + v] = s;
    return;
  }

  // ---------------- CTC forward path ------------------------------------
  const int n = blockIdx.x;
  const int g = threadIdx.x;   // owns positions 2g (blank), 2g+1 (label g)
  const int lane = g & 63;
  const int wid = __builtin_amdgcn_readfirstlane(threadIdx.x >> 6);
  __shared__ __align__(16) float mb[3][2048];  // raw x1 mantissas (writer scale)
  __shared__ int mbe[3][256];                  // writer's per-superstep exponent
  __shared__ float afin[513];

  const int len = __builtin_amdgcn_readfirstlane(ilen[n]);
  const int tl = tlen[n];

  const int* trow = tgt + n * S;
  const int tv = trow[g];
  const int tvp = (g > 0) ? trow[g - 1] : -1;
  const float skf = (g > 0 && tv != tvp) ? 1.0f : 0.0f;
  const float ep1 = (-PRIOR_SCALE * lpri[tv]) * LOG2E_F;
  const float epb = (-PRIOR_SCALE * lpri[0]) * LOG2E_F;
  const int penB = MARG * ((lane & 15) + 1);   // bcast15 per-lane distance penalty
  const int penC = MARG * ((lane & 31) + 1);   // bcast31 per-lane distance penalty

  const float* rp = lp + (size_t)n * V;
  const uint32_t RBu = (uint32_t)(N * V * 4);
  const uint32_t tvb = (uint32_t)tv * 4u;
  const uint64_t gbase = (uint64_t)(uintptr_t)rp;

  // alpha init (t=0): linear mantissas, per-lane exponent e=0
  float x0 = 0.0f, x1 = 0.0f, x2 = 0.0f;
  int e = 0;
  { float b0 = rp[0], e0 = rp[tv];
    if (g == 0) {
      x0 = fexp2(fmaf(b0, LOG2E_F, epb));
      x1 = fexp2(fmaf(e0, LOG2E_F, ep1));
    } }
  // mailbox init: 0 mantissa = no mass
  for (int idx = g; idx < 3 * 2048; idx += 256) ((float*)mb)[idx] = 0.0f;
  for (int idx = g; idx < 3 * 256; idx += 256) ((int*)mbe)[idx] = 0;

  // ---- emission ring: 8 named (label, blank) raw log-prob pairs ----
  float eR0, eR1, eR2, eR3, eR4, eR5, eR6, eR7;
  float bR0, bR1, bR2, bR3, bR4, bR5, bR6, bR7;
#define PRO(K) { uint32_t tt = (uint32_t)((1 + K < len) ? (1 + K) : (len - 1)); \
                 issue_pair(eR##K, bR##K, tt * RBu + tvb, tt * RBu, gbase); }
  PRO(0) PRO(1) PRO(2) PRO(3) PRO(4) PRO(5) PRO(6) PRO(7)
#undef PRO
  uint32_t ofB;
  { uint32_t tn = (uint32_t)((1 + K_SS < len) ? (1 + K_SS) : (len - 1));
    ofB = tn * RBu; }

  float mv0 = 0, mv1 = 0, mv2 = 0, mv3 = 0, mv4 = 0, mv5 = 0, mv6 = 0, mv7 = 0;

  PHASE_BARRIER();  // mailbox init visible

  const int nss = (len - 1 + K_SS - 1) / K_SS;
  const int P = nss + 3;

#define STEP(KK, T_, DSC_) {                                                   \
    const int t = (T_);                                                        \
    if (t < len) {                                                             \
      wait_pair(eR##KK, bR##KK);                                               \
      float e1  = fexp2(fmaf(eR##KK, LOG2E_F, ep1));                           \
      float ebl = fexp2(fmaf(bR##KK, LOG2E_F, epb));                           \
      issue_pair(eR##KK, bR##KK, ofB + tvb, ofB, gbase);                       \
      ofB += ((t + 1 + K_SS) < len) ? RBu : 0u;                                \
      float am1 = ldexpf(shr1_dpp(x1, mv##KK), (DSC_));                        \
      am1 = fminf(am1, 1.0e33f);   /* insurance vs inf */                      \
      float sel = (g == 255) ? x1 : 0.0f;                                      \
      float y0 = (x0 + am1) * ebl;                                             \
      float y1 = fmaf(skf, am1, x1 + x0) * e1;                                 \
      x2 = (x2 + sel) * ebl;                                                   \
      x0 = y0; x1 = y1;                                                        \
      if (lane == 63 && wid < 3) mb[wid][t] = y1;   /* raw, writer scale */    \
    } }

  for (int p = 0; p < P; ++p) {
    const int i = p - wid;
    if (i >= 0 && i < nss) {
      const int t0 = 1 + i * K_SS;
      int eA = 0, eB = 0;
      if (wid > 0) {
        eB = mbe[wid - 1][i];
        eA = (i > 0) ? mbe[wid - 1][i - 1] : eB;
        const float4* mrow = (const float4*)&mb[wid - 1][t0 - 1];  // 16-aligned
        float4 q0 = mrow[0], q1 = mrow[1];
        mv0 = q0.x; mv1 = q0.y; mv2 = q0.z; mv3 = q0.w;
        mv4 = q1.x; mv5 = q1.y; mv6 = q1.z; mv7 = q1.w;
      }
      // ---- renorm: per-lane peg (max -> 2^40) + decay-prefix-max relaxation ----
      int dscL, dsc0;
      {
        float mxv = fmaxf(fmaxf(x0, x1), x2);
        int ex = (int)((__float_as_uint(mxv) >> 23) & 0xFFu) - 127;
        int ecand = (mxv > 0.0f) ? (e + ex - 40) : -2000000;
        if (wid > 0 && lane == 0) ecand = imax2(ecand, imax2(eA, eB) - MARG);
        int v = ecand;
        v = imax2(v, dppi<0x111, 0xF>(v) - MARG);       // row_shr:1
        v = imax2(v, dppi<0x112, 0xF>(v) - 2 * MARG);   // row_shr:2
        v = imax2(v, dppi<0x114, 0xF>(v) - 4 * MARG);   // row_shr:4
        v = imax2(v, dppi<0x118, 0xF>(v) - 8 * MARG);   // row_shr:8
        v = imax2(v, dppi<0x142, 0xA>(v) - penB);       // row_bcast:15 -> rows 1,3
        v = imax2(v, dppi<0x143, 0xC>(v) - penC);       // row_bcast:31 -> rows 2,3
        int dsc = e - v;
        x0 = ldexpf(x0, dsc);
        x1 = ldexpf(x1, dsc);
        x2 = ldexpf(x2, dsc);
        e = v;
        if (lane == 63 && wid < 3) mbe[wid][i] = e;
        int eprevL = shr1_dpp_i(e, eB);
        dscL = eprevL - e;                 // <= MARG by relaxation
        dsc0 = (lane == 0) ? (eA - e) : dscL;  // step-0 fill is in eA scale
      }
      STEP(0, t0 + 0, dsc0)  STEP(1, t0 + 1, dscL)
      STEP(2, t0 + 2, dscL)  STEP(3, t0 + 3, dscL)
      STEP(4, t0 + 4, dscL)  STEP(5, t0 + 5, dscL)
      STEP(6, t0 + 6, dscL)  STEP(7, t0 + 7, dscL)
    }
    PHASE_BARRIER();
  }
#undef STEP

  // drain outstanding asm loads, keep dest regs live until drained
  asm volatile("s_waitcnt vmcnt(0)");
  asm volatile("" :: "v"(eR0), "v"(eR1), "v"(eR2), "v"(eR3),
                     "v"(eR4), "v"(eR5), "v"(eR6), "v"(eR7));
  asm volatile("" :: "v"(bR0), "v"(bR1), "v"(bR2), "v"(bR3),
                     "v"(bR4), "v"(bR5), "v"(bR6), "v"(bR7));

  // final alphas in absolute log2: log2(x) + e
  const float ef = (float)e;
  afin[2 * g]     = fmaxf(flog2(x0) + ef, NEGF);
  afin[2 * g + 1] = fmaxf(flog2(x1) + ef, NEGF);
  if (g == 255) afin[512] = fmaxf(flog2(x2) + ef, NEGF);
  __syncthreads();
  if (g == 0) {
    const int i1 = 2 * tl;
    float ll = lse2b(afin[i1], afin[i1 - 1]) * LN2_F;
    nll[n] = -ll / (float)tl;
  }
}

// two-stage finalize (verified in r13)
extern "C" __global__ void __launch_bounds__(256)
finalize1_kernel(const float* __restrict__ partial, int nstripes,
                 float* __restrict__ partial2) {
  const int v = threadIdx.x;
  const int b = blockIdx.x;   // 32 blocks
  float s = 0.0f;
  for (int pb = b; pb < nstripes; pb += 32) s += partial[(size_t)pb * 256 + v];
  partial2[(size_t)b * 256 + v] = s;
}
extern "C" __global__ void __launch_bounds__(256)
finalize2_kernel(const float* __restrict__ partial2, const float* __restrict__ nll,
                 float* __restrict__ out, int N) {
  const int v = threadIdx.x;
  float s = 0.0f;
#pragma unroll
  for (int b = 0; b < 32; ++b) s += partial2[(size_t)b * 256 + v];
  out[1 + v] = __logf(s);
  if (v == 0) {
    float acc = 0.0f;
#pragma unroll 8
    for (int i = 0; i < N; ++i) acc += nll[i];
    out[0] = acc / (float)N;
  }
}

// single-stage fallback (ws too small for partial2)
extern "C" __global__ void finalize_kernel(const float* __restrict__ partial, int nstripes,
                                           const float* __restrict__ nll,
                                           float* __restrict__ out, int N, int V) {
  const int v = threadIdx.x;  // 256 == V
  float s = 0.0f;
#pragma unroll 4
  for (int pb = 0; pb < nstripes; ++pb) s += partial[(size_t)pb * V + v];
  out[1 + v] = __logf(s);
  if (v == 0) {
    float acc = 0.0f;
#pragma unroll 8
    for (int i = 0; i < N; ++i) acc += nll[i];
    out[0] = acc / (float)N;
  }
}

extern "C" void kernel_launch(void* const* d_in, const int* in_sizes, int n_in,
                              void* d_out, int out_size, void* d_ws, size_t ws_size,
                              hipStream_t stream) {
  const float* lp   = (const float*)d_in[0];  // [T,N,V] fp32
  const float* lpri = (const float*)d_in[1];  // [1,V]   fp32
  const int*   tgt  = (const int*)d_in[2];    // [N,S]
  const int*   ilen = (const int*)d_in[3];    // [N]
  const int*   tlen = (const int*)d_in[4];    // [N]
  const int V = in_sizes[1];
  const int N = in_sizes[3];
  const int S = in_sizes[2] / N;
  const int T = in_sizes[0] / (N * V);

  int pblocks = 200;  // 32 + 200 = 232 blocks, all co-resident
  size_t need2stage = ((size_t)pblocks * V + 32 * 256 + 64) * sizeof(float);
  size_t need1stage = ((size_t)pblocks * V + 64) * sizeof(float);

  float* out = (float*)d_out;  // [0]=loss, [1..V]=prior logsumexp

  if (ws_size >= need2stage) {
    float* partial  = (float*)d_ws;                  // [pblocks*V]
    float* partial2 = partial + (size_t)pblocks * V; // [32*256]
    float* nll      = partial2 + 32 * 256;           // [N]
    ctc_fused_kernel<<<N + pblocks, 256, 0, stream>>>(lp, lpri, tgt, ilen, tlen,
                                                      nll, partial, pblocks, T, N, V, S);
    finalize1_kernel<<<32, 256, 0, stream>>>(partial, pblocks, partial2);
    finalize2_kernel<<<1, 256, 0, stream>>>(partial2, nll, out, N);
  } else {
    if (ws_size < need1stage) {
      long avail = (long)(ws_size / sizeof(float)) - 64;
      pblocks = (int)(avail / V);
      if (pblocks < 1) pblocks = 1;
    }
    float* partial = (float*)d_ws;
    float* nll = partial + (size_t)pblocks * V;
    ctc_fused_kernel<<<N + pblocks, 256, 0, stream>>>(lp, lpri, tgt, ilen, tlen,
                                                      nll, partial, pblocks, T, N, V, S);
    finalize_kernel<<<1, 256, 0, stream>>>(partial, pblocks, nll, out, N, V);
  }
}

// Round 20
// 185.934 us; speedup vs baseline: 1.5182x; 1.1466x over previous
//
#include <hip/hip_runtime.h>

#define PRIOR_SCALE 0.3f
#define NEGF (-1e30f)
#define LOG2E_F 1.4426950408889634f
#define LN2_F 0.6931471805599453f
#define K_SS 16    // time steps per superstep (one barrier per K_SS steps)
#define RING_D 8   // ring depth in pairs (PROVEN-SAFE; deeper corrupts r14/17/18)
#define MARG 24    // max adjacent-lane exponent gap after relaxation
#define PEG 60     // per-lane mantissa peg exponent (2^PEG)

// Fused waitcnt+barrier: ONE asm block with "memory" clobber (round-5 lesson).
#define PHASE_BARRIER() \
  asm volatile("s_waitcnt lgkmcnt(0)\n\ts_barrier" ::: "memory")

__device__ __forceinline__ float fexp2(float x) { return __builtin_amdgcn_exp2f(x); }
__device__ __forceinline__ float flog2(float x) { return __builtin_amdgcn_logf(x); }

__device__ __forceinline__ float lse2b(float a, float b) {
  float m = fmaxf(a, b);
  float d = fminf(a, b) - m;
  return m + flog2(1.0f + fexp2(d));
}

// lane-1 -> lane shift via DPP wave_shr:1. Lane 0 receives `fill`.
__device__ __forceinline__ float shr1_dpp(float x, float fill) {
  return __int_as_float(__builtin_amdgcn_update_dpp(
      __float_as_int(fill), __float_as_int(x), 0x138 /*wave_shr:1*/, 0xF, 0xF, false));
}
__device__ __forceinline__ int shr1_dpp_i(int x, int fill) {
  return __builtin_amdgcn_update_dpp(fill, x, 0x138, 0xF, 0xF, false);
}
template <int CTRL, int RM>
__device__ __forceinline__ int dppi(int x) {   // raw dpp shift (unshifted lanes keep x)
  return __builtin_amdgcn_update_dpp(x, x, CTRL, RM, 0xF, false);
}
__device__ __forceinline__ int imax2(int a, int b) { return a > b ? a : b; }

// Un-sinkable prefetch: asm-pinned global_load_dword pair.
// 8-pair ring (16 outstanding) is the proven-safe depth at ~50 VGPR pressure.
__device__ __forceinline__ void issue_pair(float& e, float& b, uint32_t offE,
                                           uint32_t offB, uint64_t base) {
  asm volatile("global_load_dword %0, %2, %4\n\t"
               "global_load_dword %1, %3, %4"
               : "=v"(e), "=v"(b)
               : "v"(offE), "v"(offB), "s"(base));
}
// Counted wait tied to consumed values via data dependency (rule #18).
__device__ __forceinline__ void wait_pair(float& e, float& b) {
  asm volatile("s_waitcnt vmcnt(14)" : "+v"(e), "+v"(b));
}

// Blocks [0,N): CTC forward, 4 time-skewed waves, 2 positions/lane, LINEAR
// per-lane block-float alphas with relaxation-bounded exponents.
// Blocks [N, N+pblocks): label-prior partial sums on the idle CUs.
extern "C" __global__ void __launch_bounds__(256, 1)
ctc_fused_kernel(const float* __restrict__ lp, const float* __restrict__ lpri,
                 const int* __restrict__ tgt, const int* __restrict__ ilen,
                 const int* __restrict__ tlen, float* __restrict__ nll,
                 float* __restrict__ partial, int pblocks,
                 int T, int N, int V, int S) {
  if ((int)blockIdx.x >= N) {
    const int pb = blockIdx.x - N;
    const int v = threadIdx.x;  // V == 256 == blockDim.x
    float s = 0.0f;
    for (int t = pb; t < T; t += pblocks) {
      const float* base = lp + (size_t)t * N * V + v;
      for (int nn = 0; nn < N; ++nn) {
        float x = base[(size_t)nn * V];
        s += (t < ilen[nn]) ? __expf(x) : 0.0f;
      }
    }
    partial[(size_t)pb * V + v] = s;
    return;
  }

  // ---------------- CTC forward path ------------------------------------
  const int n = blockIdx.x;
  const int g = threadIdx.x;   // owns positions 2g (blank), 2g+1 (label g)
  const int lane = g & 63;
  const int wid = __builtin_amdgcn_readfirstlane(threadIdx.x >> 6);
  __shared__ __align__(16) float mb[3][2048];  // raw x1 mantissas (writer scale)
  __shared__ int mbe[3][128];                  // writer's per-superstep exponent
  __shared__ float afin[513];

  const int len = __builtin_amdgcn_readfirstlane(ilen[n]);
  const int tl = tlen[n];

  const int* trow = tgt + n * S;
  const int tv = trow[g];
  const int tvp = (g > 0) ? trow[g - 1] : -1;
  const float skf = (g > 0 && tv != tvp) ? 1.0f : 0.0f;
  const float ep1 = (-PRIOR_SCALE * lpri[tv]) * LOG2E_F;
  const float epb = (-PRIOR_SCALE * lpri[0]) * LOG2E_F;
  const int penB = MARG * ((lane & 15) + 1);   // bcast15 per-lane distance penalty
  const int penC = MARG * ((lane & 31) + 1);   // bcast31 per-lane distance penalty

  const float* rp = lp + (size_t)n * V;
  const uint32_t RBu = (uint32_t)(N * V * 4);
  const uint32_t tvb = (uint32_t)tv * 4u;
  const uint64_t gbase = (uint64_t)(uintptr_t)rp;

  // alpha init (t=0): linear mantissas, per-lane exponent e=0
  float x0 = 0.0f, x1 = 0.0f, x2 = 0.0f;
  int e = 0;
  { float b0 = rp[0], e0 = rp[tv];
    if (g == 0) {
      x0 = fexp2(fmaf(b0, LOG2E_F, epb));
      x1 = fexp2(fmaf(e0, LOG2E_F, ep1));
    } }
  // mailbox init: 0 mantissa = no mass
  for (int idx = g; idx < 3 * 2048; idx += 256) ((float*)mb)[idx] = 0.0f;
  if (g < 3 * 128) ((int*)mbe)[g] = 0;

  // ---- emission ring: 8 named (label, blank) raw log-prob pairs ----
  float eR0, eR1, eR2, eR3, eR4, eR5, eR6, eR7;
  float bR0, bR1, bR2, bR3, bR4, bR5, bR6, bR7;
#define PRO(K) { uint32_t tt = (uint32_t)((1 + K < len) ? (1 + K) : (len - 1)); \
                 issue_pair(eR##K, bR##K, tt * RBu + tvb, tt * RBu, gbase); }
  PRO(0) PRO(1) PRO(2) PRO(3) PRO(4) PRO(5) PRO(6) PRO(7)
#undef PRO
  uint32_t ofB;
  { uint32_t tn = (uint32_t)((1 + RING_D < len) ? (1 + RING_D) : (len - 1));
    ofB = tn * RBu; }

  float mv0 = 0, mv1 = 0, mv2 = 0, mv3 = 0, mv4 = 0, mv5 = 0, mv6 = 0, mv7 = 0,
        mv8 = 0, mv9 = 0, mv10 = 0, mv11 = 0, mv12 = 0, mv13 = 0, mv14 = 0, mv15 = 0;

  PHASE_BARRIER();  // mailbox init visible

  const int nss = (len - 1 + K_SS - 1) / K_SS;
  const int P = nss + 3;

// KK = ring slot (0..7), MVK = mailbox fill index (0..15, step within superstep)
#define STEP(KK, MVK, T_, DSC_) {                                              \
    const int t = (T_);                                                        \
    if (t < len) {                                                             \
      wait_pair(eR##KK, bR##KK);                                               \
      float e1  = fexp2(fmaf(eR##KK, LOG2E_F, ep1));                           \
      float ebl = fexp2(fmaf(bR##KK, LOG2E_F, epb));                           \
      issue_pair(eR##KK, bR##KK, ofB + tvb, ofB, gbase);                       \
      ofB += ((t + 1 + RING_D) < len) ? RBu : 0u;                              \
      float am1 = ldexpf(shr1_dpp(x1, mv##MVK), (DSC_));                       \
      am1 = fminf(am1, 1.0e33f);   /* insurance vs inf */                      \
      float sel = (g == 255) ? x1 : 0.0f;                                      \
      float y0 = (x0 + am1) * ebl;                                             \
      float y1 = fmaf(skf, am1, x1 + x0) * e1;                                 \
      x2 = (x2 + sel) * ebl;                                                   \
      x0 = y0; x1 = y1;                                                        \
      if (lane == 63 && wid < 3) mb[wid][t] = y1;   /* raw, writer scale */    \
    } }

  for (int p = 0; p < P; ++p) {
    const int i = p - wid;
    if (i >= 0 && i < nss) {
      const int t0 = 1 + i * K_SS;
      int eA = 0, eB = 0;
      if (wid > 0) {
        eB = mbe[wid - 1][i];
        eA = (i > 0) ? mbe[wid - 1][i - 1] : eB;
        const float4* mrow = (const float4*)&mb[wid - 1][t0 - 1];  // 16-aligned
        float4 q0 = mrow[0], q1 = mrow[1], q2 = mrow[2], q3 = mrow[3];
        mv0 = q0.x;  mv1 = q0.y;  mv2 = q0.z;  mv3 = q0.w;
        mv4 = q1.x;  mv5 = q1.y;  mv6 = q1.z;  mv7 = q1.w;
        mv8 = q2.x;  mv9 = q2.y;  mv10 = q2.z; mv11 = q2.w;
        mv12 = q3.x; mv13 = q3.y; mv14 = q3.z; mv15 = q3.w;
      }
      // ---- renorm: per-lane peg (max -> 2^PEG) + decay-prefix-max relaxation ----
      int dscL, dsc0;
      {
        float mxv = fmaxf(fmaxf(x0, x1), x2);
        int ex = (int)((__float_as_uint(mxv) >> 23) & 0xFFu) - 127;
        int ecand = (mxv > 0.0f) ? (e + ex - PEG) : -2000000;
        if (wid > 0 && lane == 0) ecand = imax2(ecand, imax2(eA, eB) - MARG);
        int v = ecand;
        v = imax2(v, dppi<0x111, 0xF>(v) - MARG);       // row_shr:1
        v = imax2(v, dppi<0x112, 0xF>(v) - 2 * MARG);   // row_shr:2
        v = imax2(v, dppi<0x114, 0xF>(v) - 4 * MARG);   // row_shr:4
        v = imax2(v, dppi<0x118, 0xF>(v) - 8 * MARG);   // row_shr:8
        v = imax2(v, dppi<0x142, 0xA>(v) - penB);       // row_bcast:15 -> rows 1,3
        v = imax2(v, dppi<0x143, 0xC>(v) - penC);       // row_bcast:31 -> rows 2,3
        int dsc = e - v;
        x0 = ldexpf(x0, dsc);
        x1 = ldexpf(x1, dsc);
        x2 = ldexpf(x2, dsc);
        e = v;
        if (lane == 63 && wid < 3) mbe[wid][i] = e;
        int eprevL = shr1_dpp_i(e, eB);
        dscL = eprevL - e;                 // <= MARG by relaxation
        dsc0 = (lane == 0) ? (eA - e) : dscL;  // step-0 fill is in eA scale
      }
      STEP(0, 0, t0 + 0, dsc0)    STEP(1, 1, t0 + 1, dscL)
      STEP(2, 2, t0 + 2, dscL)    STEP(3, 3, t0 + 3, dscL)
      STEP(4, 4, t0 + 4, dscL)    STEP(5, 5, t0 + 5, dscL)
      STEP(6, 6, t0 + 6, dscL)    STEP(7, 7, t0 + 7, dscL)
      STEP(0, 8, t0 + 8, dscL)    STEP(1, 9, t0 + 9, dscL)
      STEP(2, 10, t0 + 10, dscL)  STEP(3, 11, t0 + 11, dscL)
      STEP(4, 12, t0 + 12, dscL)  STEP(5, 13, t0 + 13, dscL)
      STEP(6, 14, t0 + 14, dscL)  STEP(7, 15, t0 + 15, dscL)
    }
    PHASE_BARRIER();
  }
#undef STEP

  // drain outstanding asm loads, keep dest regs live until drained
  asm volatile("s_waitcnt vmcnt(0)");
  asm volatile("" :: "v"(eR0), "v"(eR1), "v"(eR2), "v"(eR3),
                     "v"(eR4), "v"(eR5), "v"(eR6), "v"(eR7));
  asm volatile("" :: "v"(bR0), "v"(bR1), "v"(bR2), "v"(bR3),
                     "v"(bR4), "v"(bR5), "v"(bR6), "v"(bR7));

  // final alphas in absolute log2: log2(x) + e
  const float ef = (float)e;
  afin[2 * g]     = fmaxf(flog2(x0) + ef, NEGF);
  afin[2 * g + 1] = fmaxf(flog2(x1) + ef, NEGF);
  if (g == 255) afin[512] = fmaxf(flog2(x2) + ef, NEGF);
  __syncthreads();
  if (g == 0) {
    const int i1 = 2 * tl;
    float ll = lse2b(afin[i1], afin[i1 - 1]) * LN2_F;
    nll[n] = -ll / (float)tl;
  }
}

// two-stage finalize (verified in r13/r19)
extern "C" __global__ void __launch_bounds__(256)
finalize1_kernel(const float* __restrict__ partial, int nstripes,
                 float* __restrict__ partial2) {
  const int v = threadIdx.x;
  const int b = blockIdx.x;   // 32 blocks
  float s = 0.0f;
  for (int pb = b; pb < nstripes; pb += 32) s += partial[(size_t)pb * 256 + v];
  partial2[(size_t)b * 256 + v] = s;
}
extern "C" __global__ void __launch_bounds__(256)
finalize2_kernel(const float* __restrict__ partial2, const float* __restrict__ nll,
                 float* __restrict__ out, int N) {
  const int v = threadIdx.x;
  float s = 0.0f;
#pragma unroll
  for (int b = 0; b < 32; ++b) s += partial2[(size_t)b * 256 + v];
  out[1 + v] = __logf(s);
  if (v == 0) {
    float acc = 0.0f;
#pragma unroll 8
    for (int i = 0; i < N; ++i) acc += nll[i];
    out[0] = acc / (float)N;
  }
}

// single-stage fallback (ws too small for partial2)
extern "C" __global__ void finalize_kernel(const float* __restrict__ partial, int nstripes,
                                           const float* __restrict__ nll,
                                           float* __restrict__ out, int N, int V) {
  const int v = threadIdx.x;  // 256 == V
  float s = 0.0f;
#pragma unroll 4
  for (int pb = 0; pb < nstripes; ++pb) s += partial[(size_t)pb * V + v];
  out[1 + v] = __logf(s);
  if (v == 0) {
    float acc = 0.0f;
#pragma unroll 8
    for (int i = 0; i < N; ++i) acc += nll[i];
    out[0] = acc / (float)N;
  }
}

extern "C" void kernel_launch(void* const* d_in, const int* in_sizes, int n_in,
                              void* d_out, int out_size, void* d_ws, size_t ws_size,
                              hipStream_t stream) {
  const float* lp   = (const float*)d_in[0];  // [T,N,V] fp32
  const float* lpri = (const float*)d_in[1];  // [1,V]   fp32
  const int*   tgt  = (const int*)d_in[2];    // [N,S]
  const int*   ilen = (const int*)d_in[3];    // [N]
  const int*   tlen = (const int*)d_in[4];    // [N]
  const int V = in_sizes[1];
  const int N = in_sizes[3];
  const int S = in_sizes[2] / N;
  const int T = in_sizes[0] / (N * V);

  int pblocks = 200;  // 32 + 200 = 232 blocks, all co-resident
  size_t need2stage = ((size_t)pblocks * V + 32 * 256 + 64) * sizeof(float);
  size_t need1stage = ((size_t)pblocks * V + 64) * sizeof(float);

  float* out = (float*)d_out;  // [0]=loss, [1..V]=prior logsumexp

  if (ws_size >= need2stage) {
    float* partial  = (float*)d_ws;                  // [pblocks*V]
    float* partial2 = partial + (size_t)pblocks * V; // [32*256]
    float* nll      = partial2 + 32 * 256;           // [N]
    ctc_fused_kernel<<<N + pblocks, 256, 0, stream>>>(lp, lpri, tgt, ilen, tlen,
                                                      nll, partial, pblocks, T, N, V, S);
    finalize1_kernel<<<32, 256, 0, stream>>>(partial, pblocks, partial2);
    finalize2_kernel<<<1, 256, 0, stream>>>(partial2, nll, out, N);
  } else {
    if (ws_size < need1stage) {
      long avail = (long)(ws_size / sizeof(float)) - 64;
      pblocks = (int)(avail / V);
      if (pblocks < 1) pblocks = 1;
    }
    float* partial = (float*)d_ws;
    float* nll = partial + (size_t)pblocks * V;
    ctc_fused_kernel<<<N + pblocks, 256, 0, stream>>>(lp, lpri, tgt, ilen, tlen,
                                                      nll, partial, pblocks, T, N, V, S);
    finalize_kernel<<<1, 256, 0, stream>>>(partial, pblocks, nll, out, N, V);
  }
}

// Round 21
// 178.746 us; speedup vs baseline: 1.5793x; 1.0402x over previous
//
#include <hip/hip_runtime.h>

#define PRIOR_SCALE 0.3f
#define NEGF (-1e30f)
#define LOG2E_F 1.4426950408889634f
#define LN2_F 0.6931471805599453f
#define K_SS 24    // time steps per superstep (one barrier per K_SS steps)
#define RING_D 8   // ring depth in pairs (PROVEN-SAFE; deeper corrupts r14/17/18)
#define MARG 24    // max adjacent-lane exponent gap after relaxation
#define PEG 30     // per-lane mantissa peg exponent (2^PEG): fits 24-step growth<=4b
                   // (ceiling 30+96=126<127) and decay<=7.4b (floor 30-178>-149)

// Fused waitcnt+barrier: ONE asm block with "memory" clobber (round-5 lesson).
#define PHASE_BARRIER() \
  asm volatile("s_waitcnt lgkmcnt(0)\n\ts_barrier" ::: "memory")

__device__ __forceinline__ float fexp2(float x) { return __builtin_amdgcn_exp2f(x); }
__device__ __forceinline__ float flog2(float x) { return __builtin_amdgcn_logf(x); }

__device__ __forceinline__ float lse2b(float a, float b) {
  float m = fmaxf(a, b);
  float d = fminf(a, b) - m;
  return m + flog2(1.0f + fexp2(d));
}

// lane-1 -> lane shift via DPP wave_shr:1. Lane 0 receives `fill`.
__device__ __forceinline__ float shr1_dpp(float x, float fill) {
  return __int_as_float(__builtin_amdgcn_update_dpp(
      __float_as_int(fill), __float_as_int(x), 0x138 /*wave_shr:1*/, 0xF, 0xF, false));
}
__device__ __forceinline__ int shr1_dpp_i(int x, int fill) {
  return __builtin_amdgcn_update_dpp(fill, x, 0x138, 0xF, 0xF, false);
}
template <int CTRL, int RM>
__device__ __forceinline__ int dppi(int x) {   // raw dpp shift (unshifted lanes keep x)
  return __builtin_amdgcn_update_dpp(x, x, CTRL, RM, 0xF, false);
}
__device__ __forceinline__ int imax2(int a, int b) { return a > b ? a : b; }

// Un-sinkable prefetch: asm-pinned global_load_dword pair.
// 8-pair ring (16 outstanding) is the proven-safe depth at ~50-60 VGPR pressure.
__device__ __forceinline__ void issue_pair(float& e, float& b, uint32_t offE,
                                           uint32_t offB, uint64_t base) {
  asm volatile("global_load_dword %0, %2, %4\n\t"
               "global_load_dword %1, %3, %4"
               : "=v"(e), "=v"(b)
               : "v"(offE), "v"(offB), "s"(base));
}
// Counted wait tied to consumed values via data dependency (rule #18).
__device__ __forceinline__ void wait_pair(float& e, float& b) {
  asm volatile("s_waitcnt vmcnt(14)" : "+v"(e), "+v"(b));
}

// Blocks [0,N): CTC forward, 4 time-skewed waves, 2 positions/lane, LINEAR
// per-lane block-float alphas with relaxation-bounded exponents.
// Blocks [N, N+pblocks): label-prior partial sums on the idle CUs.
extern "C" __global__ void __launch_bounds__(256, 1)
ctc_fused_kernel(const float* __restrict__ lp, const float* __restrict__ lpri,
                 const int* __restrict__ tgt, const int* __restrict__ ilen,
                 const int* __restrict__ tlen, float* __restrict__ nll,
                 float* __restrict__ partial, int pblocks,
                 int T, int N, int V, int S) {
  if ((int)blockIdx.x >= N) {
    const int pb = blockIdx.x - N;
    const int v = threadIdx.x;  // V == 256 == blockDim.x
    float s = 0.0f;
    for (int t = pb; t < T; t += pblocks) {
      const float* base = lp + (size_t)t * N * V + v;
      for (int nn = 0; nn < N; ++nn) {
        float x = base[(size_t)nn * V];
        s += (t < ilen[nn]) ? __expf(x) : 0.0f;
      }
    }
    partial[(size_t)pb * V + v] = s;
    return;
  }

  // ---------------- CTC forward path ------------------------------------
  const int n = blockIdx.x;
  const int g = threadIdx.x;   // owns positions 2g (blank), 2g+1 (label g)
  const int lane = g & 63;
  const int wid = __builtin_amdgcn_readfirstlane(threadIdx.x >> 6);
  __shared__ __align__(16) float mb[3][2048];  // raw x1 mantissas (writer scale)
  __shared__ int mbe[3][128];                  // writer's per-superstep exponent
  __shared__ float afin[513];

  const int len = __builtin_amdgcn_readfirstlane(ilen[n]);
  const int tl = tlen[n];

  const int* trow = tgt + n * S;
  const int tv = trow[g];
  const int tvp = (g > 0) ? trow[g - 1] : -1;
  const float skf = (g > 0 && tv != tvp) ? 1.0f : 0.0f;
  const float ep1 = (-PRIOR_SCALE * lpri[tv]) * LOG2E_F;
  const float epb = (-PRIOR_SCALE * lpri[0]) * LOG2E_F;
  const int penB = MARG * ((lane & 15) + 1);   // bcast15 per-lane distance penalty
  const int penC = MARG * ((lane & 31) + 1);   // bcast31 per-lane distance penalty

  const float* rp = lp + (size_t)n * V;
  const uint32_t RBu = (uint32_t)(N * V * 4);
  const uint32_t tvb = (uint32_t)tv * 4u;
  const uint64_t gbase = (uint64_t)(uintptr_t)rp;

  // alpha init (t=0): linear mantissas, per-lane exponent e=0
  float x0 = 0.0f, x1 = 0.0f, x2 = 0.0f;
  int e = 0;
  { float b0 = rp[0], e0 = rp[tv];
    if (g == 0) {
      x0 = fexp2(fmaf(b0, LOG2E_F, epb));
      x1 = fexp2(fmaf(e0, LOG2E_F, ep1));
    } }
  // mailbox init: 0 mantissa = no mass
  for (int idx = g; idx < 3 * 2048; idx += 256) ((float*)mb)[idx] = 0.0f;
  if (g < 3 * 128) ((int*)mbe)[g] = 0;

  // ---- emission ring: 8 named (label, blank) raw log-prob pairs ----
  float eR0, eR1, eR2, eR3, eR4, eR5, eR6, eR7;
  float bR0, bR1, bR2, bR3, bR4, bR5, bR6, bR7;
#define PRO(K) { uint32_t tt = (uint32_t)((1 + K < len) ? (1 + K) : (len - 1)); \
                 issue_pair(eR##K, bR##K, tt * RBu + tvb, tt * RBu, gbase); }
  PRO(0) PRO(1) PRO(2) PRO(3) PRO(4) PRO(5) PRO(6) PRO(7)
#undef PRO
  uint32_t ofB;
  { uint32_t tn = (uint32_t)((1 + RING_D < len) ? (1 + RING_D) : (len - 1));
    ofB = tn * RBu; }

  float mv0 = 0, mv1 = 0, mv2 = 0, mv3 = 0, mv4 = 0, mv5 = 0, mv6 = 0, mv7 = 0,
        mv8 = 0, mv9 = 0, mv10 = 0, mv11 = 0, mv12 = 0, mv13 = 0, mv14 = 0,
        mv15 = 0, mv16 = 0, mv17 = 0, mv18 = 0, mv19 = 0, mv20 = 0, mv21 = 0,
        mv22 = 0, mv23 = 0;

  PHASE_BARRIER();  // mailbox init visible

  const int nss = (len - 1 + K_SS - 1) / K_SS;   // <= 84 with K_SS=24
  const int P = nss + 3;

// KK = ring slot (0..7), MVK = mailbox fill index (0..23, step within superstep)
#define STEP(KK, MVK, T_, DSC_) {                                              \
    const int t = (T_);                                                        \
    if (t < len) {                                                             \
      wait_pair(eR##KK, bR##KK);                                               \
      float e1  = fexp2(fmaf(eR##KK, LOG2E_F, ep1));                           \
      float ebl = fexp2(fmaf(bR##KK, LOG2E_F, epb));                           \
      issue_pair(eR##KK, bR##KK, ofB + tvb, ofB, gbase);                       \
      ofB += ((t + 1 + RING_D) < len) ? RBu : 0u;                              \
      float am1 = ldexpf(shr1_dpp(x1, mv##MVK), (DSC_));                       \
      am1 = fminf(am1, 1.0e33f);   /* insurance vs inf */                      \
      float sel = (g == 255) ? x1 : 0.0f;                                      \
      float y0 = (x0 + am1) * ebl;                                             \
      float y1 = fmaf(skf, am1, x1 + x0) * e1;                                 \
      x2 = (x2 + sel) * ebl;                                                   \
      x0 = y0; x1 = y1;                                                        \
      if (lane == 63 && wid < 3) mb[wid][t] = y1;   /* raw, writer scale */    \
    } }

  for (int p = 0; p < P; ++p) {
    const int i = p - wid;
    if (i >= 0 && i < nss) {
      const int t0 = 1 + i * K_SS;
      int eA = 0, eB = 0;
      if (wid > 0) {
        eB = mbe[wid - 1][i];
        eA = (i > 0) ? mbe[wid - 1][i - 1] : eB;
        // mb[wid-1][t0-1 .. t0+22]; t0-1 = i*24 floats = 96 B, 16-B aligned
        const float4* mrow = (const float4*)&mb[wid - 1][t0 - 1];
        float4 q0 = mrow[0], q1 = mrow[1], q2 = mrow[2],
               q3 = mrow[3], q4 = mrow[4], q5 = mrow[5];
        mv0 = q0.x;  mv1 = q0.y;  mv2 = q0.z;  mv3 = q0.w;
        mv4 = q1.x;  mv5 = q1.y;  mv6 = q1.z;  mv7 = q1.w;
        mv8 = q2.x;  mv9 = q2.y;  mv10 = q2.z; mv11 = q2.w;
        mv12 = q3.x; mv13 = q3.y; mv14 = q3.z; mv15 = q3.w;
        mv16 = q4.x; mv17 = q4.y; mv18 = q4.z; mv19 = q4.w;
        mv20 = q5.x; mv21 = q5.y; mv22 = q5.z; mv23 = q5.w;
      }
      // ---- renorm: per-lane peg (max -> 2^PEG) + decay-prefix-max relaxation ----
      int dscL, dsc0;
      {
        float mxv = fmaxf(fmaxf(x0, x1), x2);
        int ex = (int)((__float_as_uint(mxv) >> 23) & 0xFFu) - 127;
        int ecand = (mxv > 0.0f) ? (e + ex - PEG) : -2000000;
        if (wid > 0 && lane == 0) ecand = imax2(ecand, imax2(eA, eB) - MARG);
        int v = ecand;
        v = imax2(v, dppi<0x111, 0xF>(v) - MARG);       // row_shr:1
        v = imax2(v, dppi<0x112, 0xF>(v) - 2 * MARG);   // row_shr:2
        v = imax2(v, dppi<0x114, 0xF>(v) - 4 * MARG);   // row_shr:4
        v = imax2(v, dppi<0x118, 0xF>(v) - 8 * MARG);   // row_shr:8
        v = imax2(v, dppi<0x142, 0xA>(v) - penB);       // row_bcast:15 -> rows 1,3
        v = imax2(v, dppi<0x143, 0xC>(v) - penC);       // row_bcast:31 -> rows 2,3
        int dsc = e - v;
        x0 = ldexpf(x0, dsc);
        x1 = ldexpf(x1, dsc);
        x2 = ldexpf(x2, dsc);
        e = v;
        if (lane == 63 && wid < 3) mbe[wid][i] = e;
        int eprevL = shr1_dpp_i(e, eB);
        dscL = eprevL - e;                 // <= MARG by relaxation
        dsc0 = (lane == 0) ? (eA - e) : dscL;  // step-0 fill is in eA scale
      }
      STEP(0, 0, t0 + 0, dsc0)    STEP(1, 1, t0 + 1, dscL)
      STEP(2, 2, t0 + 2, dscL)    STEP(3, 3, t0 + 3, dscL)
      STEP(4, 4, t0 + 4, dscL)    STEP(5, 5, t0 + 5, dscL)
      STEP(6, 6, t0 + 6, dscL)    STEP(7, 7, t0 + 7, dscL)
      STEP(0, 8, t0 + 8, dscL)    STEP(1, 9, t0 + 9, dscL)
      STEP(2, 10, t0 + 10, dscL)  STEP(3, 11, t0 + 11, dscL)
      STEP(4, 12, t0 + 12, dscL)  STEP(5, 13, t0 + 13, dscL)
      STEP(6, 14, t0 + 14, dscL)  STEP(7, 15, t0 + 15, dscL)
      STEP(0, 16, t0 + 16, dscL)  STEP(1, 17, t0 + 17, dscL)
      STEP(2, 18, t0 + 18, dscL)  STEP(3, 19, t0 + 19, dscL)
      STEP(4, 20, t0 + 20, dscL)  STEP(5, 21, t0 + 21, dscL)
      STEP(6, 22, t0 + 22, dscL)  STEP(7, 23, t0 + 23, dscL)
    }
    PHASE_BARRIER();
  }
#undef STEP

  // drain outstanding asm loads, keep dest regs live until drained
  asm volatile("s_waitcnt vmcnt(0)");
  asm volatile("" :: "v"(eR0), "v"(eR1), "v"(eR2), "v"(eR3),
                     "v"(eR4), "v"(eR5), "v"(eR6), "v"(eR7));
  asm volatile("" :: "v"(bR0), "v"(bR1), "v"(bR2), "v"(bR3),
                     "v"(bR4), "v"(bR5), "v"(bR6), "v"(bR7));

  // final alphas in absolute log2: log2(x) + e
  const float ef = (float)e;
  afin[2 * g]     = fmaxf(flog2(x0) + ef, NEGF);
  afin[2 * g + 1] = fmaxf(flog2(x1) + ef, NEGF);
  if (g == 255) afin[512] = fmaxf(flog2(x2) + ef, NEGF);
  __syncthreads();
  if (g == 0) {
    const int i1 = 2 * tl;
    float ll = lse2b(afin[i1], afin[i1 - 1]) * LN2_F;
    nll[n] = -ll / (float)tl;
  }
}

// two-stage finalize (verified in r13/r19/r20)
extern "C" __global__ void __launch_bounds__(256)
finalize1_kernel(const float* __restrict__ partial, int nstripes,
                 float* __restrict__ partial2) {
  const int v = threadIdx.x;
  const int b = blockIdx.x;   // 32 blocks
  float s = 0.0f;
  for (int pb = b; pb < nstripes; pb += 32) s += partial[(size_t)pb * 256 + v];
  partial2[(size_t)b * 256 + v] = s;
}
extern "C" __global__ void __launch_bounds__(256)
finalize2_kernel(const float* __restrict__ partial2, const float* __restrict__ nll,
                 float* __restrict__ out, int N) {
  const int v = threadIdx.x;
  float s = 0.0f;
#pragma unroll
  for (int b = 0; b < 32; ++b) s += partial2[(size_t)b * 256 + v];
  out[1 + v] = __logf(s);
  if (v == 0) {
    float acc = 0.0f;
#pragma unroll 8
    for (int i = 0; i < N; ++i) acc += nll[i];
    out[0] = acc / (float)N;
  }
}

// single-stage fallback (ws too small for partial2)
extern "C" __global__ void finalize_kernel(const float* __restrict__ partial, int nstripes,
                                           const float* __restrict__ nll,
                                           float* __restrict__ out, int N, int V) {
  const int v = threadIdx.x;  // 256 == V
  float s = 0.0f;
#pragma unroll 4
  for (int pb = 0; pb < nstripes; ++pb) s += partial[(size_t)pb * V + v];
  out[1 + v] = __logf(s);
  if (v == 0) {
    float acc = 0.0f;
#pragma unroll 8
    for (int i = 0; i < N; ++i) acc += nll[i];
    out[0] = acc / (float)N;
  }
}

extern "C" void kernel_launch(void* const* d_in, const int* in_sizes, int n_in,
                              void* d_out, int out_size, void* d_ws, size_t ws_size,
                              hipStream_t stream) {
  const float* lp   = (const float*)d_in[0];  // [T,N,V] fp32
  const float* lpri = (const float*)d_in[1];  // [1,V]   fp32
  const int*   tgt  = (const int*)d_in[2];    // [N,S]
  const int*   ilen = (const int*)d_in[3];    // [N]
  const int*   tlen = (const int*)d_in[4];    // [N]
  const int V = in_sizes[1];
  const int N = in_sizes[3];
  const int S = in_sizes[2] / N;
  const int T = in_sizes[0] / (N * V);

  int pblocks = 200;  // 32 + 200 = 232 blocks, all co-resident
  size_t need2stage = ((size_t)pblocks * V + 32 * 256 + 64) * sizeof(float);
  size_t need1stage = ((size_t)pblocks * V + 64) * sizeof(float);

  float* out = (float*)d_out;  // [0]=loss, [1..V]=prior logsumexp

  if (ws_size >= need2stage) {
    float* partial  = (float*)d_ws;                  // [pblocks*V]
    float* partial2 = partial + (size_t)pblocks * V; // [32*256]
    float* nll      = partial2 + 32 * 256;           // [N]
    ctc_fused_kernel<<<N + pblocks, 256, 0, stream>>>(lp, lpri, tgt, ilen, tlen,
                                                      nll, partial, pblocks, T, N, V, S);
    finalize1_kernel<<<32, 256, 0, stream>>>(partial, pblocks, partial2);
    finalize2_kernel<<<1, 256, 0, stream>>>(partial2, nll, out, N);
  } else {
    if (ws_size < need1stage) {
      long avail = (long)(ws_size / sizeof(float)) - 64;
      pblocks = (int)(avail / V);
      if (pblocks < 1) pblocks = 1;
    }
    float* partial = (float*)d_ws;
    float* nll = partial + (size_t)pblocks * V;
    ctc_fused_kernel<<<N + pblocks, 256, 0, stream>>>(lp, lpri, tgt, ilen, tlen,
                                                      nll, partial, pblocks, T, N, V, S);
    finalize_kernel<<<1, 256, 0, stream>>>(partial, pblocks, nll, out, N, V);
  }
}